// Round 23
// baseline (208.911 us; speedup 1.0000x reference)
//
#include <hip/hip_runtime.h>

typedef short bf16x8 __attribute__((ext_vector_type(8)));
typedef float f32x4 __attribute__((ext_vector_type(4)));
typedef unsigned short us4 __attribute__((ext_vector_type(4)));

#define B_ 16
#define S_ 2048
#define F_ 512
#define U_ 512
#define NROWS (B_ * S_)          // 32768

#define MFMA(a, b, c)  __builtin_amdgcn_mfma_f32_16x16x32_bf16((a), (b), (c), 0, 0, 0)
#define MFMA8(a, b, c) __builtin_amdgcn_mfma_f32_16x16x32_fp8_fp8((a), (b), (c), 0, 0, 0)

// async global->LDS, 16B per lane; LDS dest = uniform base + lane*16
#define GL16(g, s) __builtin_amdgcn_global_load_lds( \
    (const __attribute__((address_space(1))) unsigned int*)(g), \
    (__attribute__((address_space(3))) unsigned int*)(s), 16, 0, 0)

__device__ __forceinline__ unsigned short f2b(float f) {
    unsigned u = __builtin_bit_cast(unsigned, f);
    return (unsigned short)((u + 0x7FFFu + ((u >> 16) & 1u)) >> 16);
}
__device__ __forceinline__ float b2f(unsigned short s) {
    return __builtin_bit_cast(float, (unsigned)s << 16);
}

// ---------------------------------------------------------------------------
// Fused converts: blocks 0..2047 convert x fp32->bf16; blocks 2048..2559
// transpose W_q/W_k fp32 -> Wt bf16 [z][n][k].
// ---------------------------------------------------------------------------
__global__ __launch_bounds__(256) void conv_xw(
    const float* __restrict__ x,
    const float* __restrict__ Wq,
    const float* __restrict__ Wk,
    unsigned short* __restrict__ xb,
    unsigned short* __restrict__ Wt)
{
    const int d = blockIdx.x;
    if (d < 2048) {
        const size_t n8 = (size_t)NROWS * F_ / 8;
        const size_t stride = (size_t)2048 * 256;
        for (size_t i = (size_t)d * 256 + threadIdx.x; i < n8; i += stride) {
            const float4 a = ((const float4*)x)[i * 2];
            const float4 b = ((const float4*)x)[i * 2 + 1];
            us4 lo, hi;
            lo.x = f2b(a.x); lo.y = f2b(a.y); lo.z = f2b(a.z); lo.w = f2b(a.w);
            hi.x = f2b(b.x); hi.y = f2b(b.y); hi.z = f2b(b.z); hi.w = f2b(b.w);
            ((us4*)xb)[i * 2]     = lo;
            ((us4*)xb)[i * 2 + 1] = hi;
        }
    } else {
        __shared__ float tile[32][33];
        const int idx = d - 2048;              // 0..511
        const int z = idx >> 8, rem = idx & 255;
        const int k0 = (rem >> 4) * 32, n0 = (rem & 15) * 32;
        const float* W = (z == 0) ? Wq : Wk;
        unsigned short* out = Wt + (size_t)z * F_ * U_;
        const int r = threadIdx.x >> 5, c = threadIdx.x & 31;
        #pragma unroll
        for (int p = 0; p < 4; ++p)
            tile[p * 8 + r][c] = W[(size_t)(k0 + p * 8 + r) * U_ + n0 + c];
        __syncthreads();
        #pragma unroll
        for (int p = 0; p < 4; ++p)
            out[(size_t)(n0 + p * 8 + r) * F_ + k0 + c] = f2b(tile[c][p * 8 + r]);
    }
}

// ---------------------------------------------------------------------------
// Q/K GEMM v5: BN=128, reg-prefetch dbuf, one barrier/kc, XCD-chunked.
// Outputs FP8 E4M3, UNSCALED: Qb8 linear; Kb8 with per-row unit swizzle
// (unit ^= row&31).  2048 blocks.
// ---------------------------------------------------------------------------
__global__ __launch_bounds__(256) void qk_gemm(
    const unsigned short* __restrict__ xb,
    const unsigned short* __restrict__ Wt,
    unsigned char* __restrict__ Qb8,
    unsigned char* __restrict__ Kb8)
{
    __shared__ char smem[128 * 65 * 4];                 // 33280 B
    unsigned short* Xs0 = (unsigned short*)smem;        // [128][32]
    unsigned short* Ws0 = Xs0 + 128 * 32;               // [128][32]
    unsigned short* Xs1 = Ws0 + 128 * 32;
    unsigned short* Ws1 = Xs1 + 128 * 32;               // 32 KB dbuf
    float* Cs = (float*)smem;                           // [128][65] epilogue

    const int dd = blockIdx.x;                 // 0..2047
    const int gi = (dd & 7) * 256 + (dd >> 3); // contiguous 256 per XCD
    const int mtile = gi >> 3;                 // 0..255
    const int sub = gi & 7;
    const int z = sub >> 2;                    // 0..1
    const int bm = mtile * 128;
    const int bn = (sub & 3) * 128;

    const unsigned short* Wz = Wt + (size_t)z * F_ * U_;
    const int t = threadIdx.x;
    const int w = t >> 6, l = t & 63, lr = l & 15, lg = l >> 4;
    const int vxA = (lr >> 1) & 3;             // read-side slot XOR

    const int row0 = t >> 2,         slot0 = t & 3;     // rows 0..63
    const int row1 = (256 + t) >> 2, slot1 = t & 3;     // rows 64..127

    f32x4 acc[2][8];
    #pragma unroll
    for (int mt = 0; mt < 2; ++mt)
        #pragma unroll
        for (int nt = 0; nt < 8; ++nt)
            acc[mt][nt] = (f32x4){0.f, 0.f, 0.f, 0.f};

    bf16x8 xr0, xr1, wr0, wr1;
    xr0 = *(const bf16x8*)&xb[(size_t)(bm + row0) * F_ + slot0 * 8];
    xr1 = *(const bf16x8*)&xb[(size_t)(bm + row1) * F_ + slot1 * 8];
    wr0 = *(const bf16x8*)&Wz[(size_t)(bn + row0) * F_ + slot0 * 8];
    wr1 = *(const bf16x8*)&Wz[(size_t)(bn + row1) * F_ + slot1 * 8];
    *(bf16x8*)&Xs0[row0 * 32 + ((slot0 ^ ((row0 >> 1) & 3)) * 8)] = xr0;
    *(bf16x8*)&Xs0[row1 * 32 + ((slot1 ^ ((row1 >> 1) & 3)) * 8)] = xr1;
    *(bf16x8*)&Ws0[row0 * 32 + ((slot0 ^ ((row0 >> 1) & 3)) * 8)] = wr0;
    *(bf16x8*)&Ws0[row1 * 32 + ((slot1 ^ ((row1 >> 1) & 3)) * 8)] = wr1;
    xr0 = *(const bf16x8*)&xb[(size_t)(bm + row0) * F_ + 32 + slot0 * 8];
    xr1 = *(const bf16x8*)&xb[(size_t)(bm + row1) * F_ + 32 + slot1 * 8];
    wr0 = *(const bf16x8*)&Wz[(size_t)(bn + row0) * F_ + 32 + slot0 * 8];
    wr1 = *(const bf16x8*)&Wz[(size_t)(bn + row1) * F_ + 32 + slot1 * 8];
    __syncthreads();

    int cur = 0;
    for (int kc = 0; kc < 16; ++kc) {
        unsigned short* Xc = cur ? Xs1 : Xs0;
        unsigned short* Wc = cur ? Ws1 : Ws0;
        if (kc < 15) {
            unsigned short* Xn = cur ? Xs0 : Xs1;
            unsigned short* Wn = cur ? Ws0 : Ws1;
            *(bf16x8*)&Xn[row0 * 32 + ((slot0 ^ ((row0 >> 1) & 3)) * 8)] = xr0;
            *(bf16x8*)&Xn[row1 * 32 + ((slot1 ^ ((row1 >> 1) & 3)) * 8)] = xr1;
            *(bf16x8*)&Wn[row0 * 32 + ((slot0 ^ ((row0 >> 1) & 3)) * 8)] = wr0;
            *(bf16x8*)&Wn[row1 * 32 + ((slot1 ^ ((row1 >> 1) & 3)) * 8)] = wr1;
            const int k2 = ((kc + 2 < 16) ? kc + 2 : 15) * 32;
            xr0 = *(const bf16x8*)&xb[(size_t)(bm + row0) * F_ + k2 + slot0 * 8];
            xr1 = *(const bf16x8*)&xb[(size_t)(bm + row1) * F_ + k2 + slot1 * 8];
            wr0 = *(const bf16x8*)&Wz[(size_t)(bn + row0) * F_ + k2 + slot0 * 8];
            wr1 = *(const bf16x8*)&Wz[(size_t)(bn + row1) * F_ + k2 + slot1 * 8];
        }
        const bf16x8 a0 = *(const bf16x8*)&Xc[(w * 32 + lr) * 32 + ((lg ^ vxA) * 8)];
        const bf16x8 a1 = *(const bf16x8*)&Xc[(w * 32 + 16 + lr) * 32 + ((lg ^ vxA) * 8)];
        #pragma unroll
        for (int nt = 0; nt < 8; ++nt) {
            const bf16x8 bb = *(const bf16x8*)&Wc[(nt * 16 + lr) * 32 + ((lg ^ vxA) * 8)];
            acc[0][nt] = MFMA(a0, bb, acc[0][nt]);
            acc[1][nt] = MFMA(a1, bb, acc[1][nt]);
        }
        __syncthreads();
        cur ^= 1;
    }

    unsigned char* out8 = (z == 0) ? Qb8 : Kb8;
    #pragma unroll
    for (int p = 0; p < 2; ++p) {
        if (p) __syncthreads();
        #pragma unroll
        for (int mt = 0; mt < 2; ++mt)
            #pragma unroll
            for (int nt = 0; nt < 4; ++nt)
                #pragma unroll
                for (int j = 0; j < 4; ++j)
                    Cs[(w * 32 + mt * 16 + lg * 4 + j) * 65 + nt * 16 + lr]
                        = acc[mt][p * 4 + nt][j];
        __syncthreads();
        const int row = t >> 1, half = t & 1;
        const int rr = row & 31;
        #pragma unroll
        for (int v = 0; v < 4; ++v) {
            const float* c = &Cs[row * 65 + half * 32 + v * 8];
            int lo = __builtin_amdgcn_cvt_pk_fp8_f32(c[0], c[1], 0, false);
            lo     = __builtin_amdgcn_cvt_pk_fp8_f32(c[2], c[3], lo, true);
            int hi = __builtin_amdgcn_cvt_pk_fp8_f32(c[4], c[5], 0, false);
            hi     = __builtin_amdgcn_cvt_pk_fp8_f32(c[6], c[7], hi, true);
            const int u  = (bn >> 3) + p * 8 + half * 4 + v;  // 8B unit 0..63
            const int pu = (z == 0) ? u : (u ^ rr);           // K: row swizzle
            unsigned* dst = (unsigned*)&out8[(size_t)(bm + row) * 512 + pu * 8];
            dst[0] = (unsigned)lo;
            dst[1] = (unsigned)hi;
        }
    }
}

// ---------------------------------------------------------------------------
// attn_w v9: QUARTER-SPLIT, 4 blocks/CU.  1024 blocks (b, qblk, h=0..3),
// each 128 q x 512 keys (16 iters).  fp8 QK^T, m==0 softmax, p~ fp8 out.
// 4 independent barrier domains per CU hide the barrier/DMA stalls.
// ---------------------------------------------------------------------------
__global__ __launch_bounds__(256, 4) void attn_w(
    const unsigned char* __restrict__ Qb8,
    const unsigned char* __restrict__ Kb8,
    unsigned char* __restrict__ ptil,              // [32768 q][2048 k] fp8
    float* __restrict__ lpart)                     // [16][4][2048]
{
    __shared__ unsigned char Ks8[2][32 * 512];     // 32.0 KB
    __shared__ unsigned char Ps8[128 * 48];        //  6.0 KB -> 38.9 KB total

    const int d = blockIdx.x;                      // 0..1023
    const int b    = ((d & 7) << 1) | (d >> 9);    // XCD j -> batches 2j,2j+1
    const int qblk = (d >> 3) & 15;                // 0..15
    const int h    = (d >> 7) & 3;                 // key-quarter
    const int t = threadIdx.x;                     // 0..255
    const int qs = t >> 6;                         // q-wave 0..3
    const int l = t & 63, lr = l & 15, lg = l >> 4;
    const float sc = 0.044194173824159216f;        // 1/sqrt(512)

    // ---- Q fragments (fp8, 8B per kc-chunk) for the wave's 32 queries ----
    long qA[16], qB[16];
    {
        const unsigned char* qg =
            Qb8 + (size_t)(b * S_ + qblk * 128 + qs * 32 + lr) * 512 + lg * 8;
        #pragma unroll
        for (int kc = 0; kc < 16; ++kc) {
            qA[kc] = *(const long*)(qg + kc * 32);
            qB[kc] = *(const long*)(qg + 16 * 512 + kc * 32);
        }
    }

    const unsigned char* kgb = Kb8 + (size_t)b * S_ * 512 + (size_t)h * 512 * 512;
    unsigned char* pbase = ptil + ((size_t)(b * 16 + qblk) * 128) * 2048 + h * 512;

    // wave qs stages rows qs*8..qs*8+7 (4 ops x 1 KB = 2 rows each)
    #define STAGE(it_, buf_)                                                     \
    do {                                                                         \
        const unsigned char* ksrc_ = kgb + ((size_t)(it_) * 32) * 512;           \
        _Pragma("unroll")                                                        \
        for (int i_ = 0; i_ < 4; ++i_) {                                         \
            const int r_ = qs * 8 + i_ * 2;                                      \
            GL16(ksrc_ + (size_t)r_ * 512 + l * 16, &Ks8[buf_][r_ * 512]);       \
        }                                                                        \
    } while (0)

    STAGE(0, 0);
    __syncthreads();

    float l0 = 0.f, l1 = 0.f;
    int cur = 0;

    for (int it = 0; it < 16; ++it) {
        const int nt = (it + 1 < 16) ? it + 1 : it;
        STAGE(nt, cur ^ 1);

        f32x4 sA0 = (f32x4){0.f,0.f,0.f,0.f};
        f32x4 sA1 = (f32x4){0.f,0.f,0.f,0.f};
        f32x4 sB0 = (f32x4){0.f,0.f,0.f,0.f};
        f32x4 sB1 = (f32x4){0.f,0.f,0.f,0.f};
        #pragma unroll
        for (int kc = 0; kc < 16; ++kc) {
            const int u = kc * 4 + lg;
            const long k0 = *(const long*)&Ks8[cur][lr * 512 + ((u ^ lr) * 8)];
            const long k1 = *(const long*)&Ks8[cur][(16 + lr) * 512 + ((u ^ (16 + lr)) * 8)];
            sA0 = MFMA8(k0, qA[kc], sA0);
            sA1 = MFMA8(k1, qA[kc], sA1);
            sB0 = MFMA8(k0, qB[kc], sB0);
            sB1 = MFMA8(k1, qB[kc], sB1);
        }

        float eA0[4], eA1[4], eB0[4], eB1[4];
        float sum0 = 0.f, sum1 = 0.f;
        #pragma unroll
        for (int j = 0; j < 4; ++j) {
            eA0[j] = __expf(sA0[j] * sc); eA1[j] = __expf(sA1[j] * sc);
            eB0[j] = __expf(sB0[j] * sc); eB1[j] = __expf(sB1[j] * sc);
            sum0 += eA0[j] + eA1[j];
            sum1 += eB0[j] + eB1[j];
        }
        sum0 += __shfl_xor(sum0, 16); sum0 += __shfl_xor(sum0, 32);
        sum1 += __shfl_xor(sum1, 16); sum1 += __shfl_xor(sum1, 32);
        l0 += sum0; l1 += sum1;

        // ---- pack p~ to fp8, deposit into wave-private LDS strip ----
        int dA0 = __builtin_amdgcn_cvt_pk_fp8_f32(eA0[0], eA0[1], 0, false);
        dA0     = __builtin_amdgcn_cvt_pk_fp8_f32(eA0[2], eA0[3], dA0, true);
        int dA1 = __builtin_amdgcn_cvt_pk_fp8_f32(eA1[0], eA1[1], 0, false);
        dA1     = __builtin_amdgcn_cvt_pk_fp8_f32(eA1[2], eA1[3], dA1, true);
        int dB0 = __builtin_amdgcn_cvt_pk_fp8_f32(eB0[0], eB0[1], 0, false);
        dB0     = __builtin_amdgcn_cvt_pk_fp8_f32(eB0[2], eB0[3], dB0, true);
        int dB1 = __builtin_amdgcn_cvt_pk_fp8_f32(eB1[0], eB1[1], 0, false);
        dB1     = __builtin_amdgcn_cvt_pk_fp8_f32(eB1[2], eB1[3], dB1, true);
        unsigned* Pu = (unsigned*)Ps8;
        Pu[(qs * 32 + lr) * 12 + lg]          = (unsigned)dA0;
        Pu[(qs * 32 + lr) * 12 + 4 + lg]      = (unsigned)dA1;
        Pu[(qs * 32 + 16 + lr) * 12 + lg]     = (unsigned)dB0;
        Pu[(qs * 32 + 16 + lr) * 12 + 4 + lg] = (unsigned)dB1;

        // ---- wave-local copy-out (32 rows x 32B per wave) ----
        {
            const int rl = l >> 1, seg = l & 1;
            const int row = qs * 32 + rl;
            *(bf16x8*)&pbase[(size_t)row * 2048 + it * 32 + seg * 16]
                = *(const bf16x8*)&Ps8[row * 48 + seg * 16];
        }

        __syncthreads();                           // K dbuf swap + DMA drain
        cur ^= 1;
    }

    if (lg == 0) {
        lpart[((size_t)b * 4 + h) * 2048 + qblk * 128 + qs * 32 + lr]      = l0;
        lpart[((size_t)b * 4 + h) * 2048 + qblk * 128 + qs * 32 + 16 + lr] = l1;
    }
    #undef STAGE
}

// ---------------------------------------------------------------------------
// w_red: 2048 blocks (b, qsl, kc).  invl from the 4 lpart quarters.
// wred[b][qsl][kc*128+j] = sum_q p~[q][kc*128+j] / sum_h l_h[q].
// ---------------------------------------------------------------------------
__global__ __launch_bounds__(256) void w_red(
    const unsigned char* __restrict__ ptil,
    const float* __restrict__ lpart,               // [16][4][2048]
    float* __restrict__ wred)                      // [16][8][2048]
{
    const int d = blockIdx.x;                      // 0..2047
    const int b = d >> 7, qsl = (d >> 4) & 7, kc = d & 15;
    const int t = threadIdx.x;
    __shared__ float linv[256];
    __shared__ float wsum[8][132];

    if (t < 256) {
        float s = 0.f;
        #pragma unroll
        for (int hh = 0; hh < 4; ++hh)
            s += lpart[((size_t)b * 4 + hh) * 2048 + qsl * 256 + t];
        linv[t] = 1.f / s;
    }
    __syncthreads();

    const int kk = (t & 31) * 4, qp = t >> 5;      // 32 k-slots x 8 q-parallel
    float a0 = 0.f, a1 = 0.f, a2 = 0.f, a3 = 0.f;
    const unsigned char* pb = ptil + (size_t)b * 2048 * 2048
                            + (size_t)(qsl * 256) * 2048 + kc * 128 + kk;
    #pragma unroll 4
    for (int qq = qp; qq < 256; qq += 8) {
        const int v = *(const int*)&pb[(size_t)qq * 2048];
        const float li = linv[qq];
        a0 += __builtin_amdgcn_cvt_f32_fp8(v, 0) * li;
        a1 += __builtin_amdgcn_cvt_f32_fp8(v, 1) * li;
        a2 += __builtin_amdgcn_cvt_f32_fp8(v, 2) * li;
        a3 += __builtin_amdgcn_cvt_f32_fp8(v, 3) * li;
    }
    wsum[qp][kk + 0] = a0; wsum[qp][kk + 1] = a1;
    wsum[qp][kk + 2] = a2; wsum[qp][kk + 3] = a3;
    __syncthreads();
    if (t < 128) {
        float s = 0.f;
        #pragma unroll
        for (int p = 0; p < 8; ++p) s += wsum[p][t];
        wred[((size_t)(b * 8 + qsl)) * 2048 + kc * 128 + t] = s;
    }
}

// ---------------------------------------------------------------------------
// xw_part: block (b, kc).  wk from wred partials, then
// phase B (fp32 x): xw[f] = sum_k wk * x[b][k][f].
// ---------------------------------------------------------------------------
__global__ __launch_bounds__(256) void xw_part(
    const float* __restrict__ x,
    const float* __restrict__ wred,                // [16][8][2048]
    float* __restrict__ xw_out)                    // [16][16][512]
{
    const int b = blockIdx.x >> 4, kc = blockIdx.x & 15;
    const int t = threadIdx.x;
    __shared__ float wk[128];

    if (t < 128) {
        float s = 0.f;
        #pragma unroll
        for (int p = 0; p < 8; ++p)
            s += wred[((size_t)(b * 8 + p)) * 2048 + kc * 128 + t];
        wk[t] = s;
    }
    __syncthreads();

    const float* xp = x + ((size_t)(b * S_ + kc * 128)) * F_ + t * 2;
    float2 acc = {0.f, 0.f};
    #pragma unroll 8
    for (int k = 0; k < 128; ++k) {
        const float2 v = *(const float2*)(xp + (size_t)k * F_);
        acc.x += wk[k] * v.x;
        acc.y += wk[k] * v.y;
    }
    float* o = xw_out + (size_t)(b * 16 + kc) * F_ + t * 2;
    o[0] = acc.x; o[1] = acc.y;
}

// ---------------------------------------------------------------------------
// final: out[b][u] = (1/2048) * sum_f xw[b][f] * Wv[f][u]   (fp32)
// ---------------------------------------------------------------------------
__global__ __launch_bounds__(512) void final_out(
    const float* __restrict__ xw_parts,            // [16][16][512]
    const float* __restrict__ Wv,
    float* __restrict__ out)
{
    const int b = blockIdx.x, t = threadIdx.x;     // 512 threads = u
    __shared__ float xw[512];
    float s = 0.f;
    #pragma unroll
    for (int p = 0; p < 16; ++p)
        s += xw_parts[(size_t)(b * 16 + p) * F_ + t];
    xw[t] = s;
    __syncthreads();
    float acc = 0.f;
    #pragma unroll 8
    for (int f = 0; f < F_; ++f)
        acc += xw[f] * Wv[(size_t)f * U_ + t];
    out[(size_t)b * U_ + t] = acc * (1.0f / (float)S_);
}

extern "C" void kernel_launch(void* const* d_in, const int* in_sizes, int n_in,
                              void* d_out, int out_size, void* d_ws, size_t ws_size,
                              hipStream_t stream)
{
    const float* x  = (const float*)d_in[0];
    const float* Wq = (const float*)d_in[1];
    const float* Wk = (const float*)d_in[2];
    const float* Wv = (const float*)d_in[3];
    float* out = (float*)d_out;

    unsigned short* ws = (unsigned short*)d_ws;
    const size_t XB_OFF = 0;                               // [32768][512] bf16
    const size_t WT_OFF = XB_OFF + (size_t)NROWS * F_;     // 2x[512][512] bf16
    const size_t QB_OFF = WT_OFF + 2ull * F_ * U_;         // [32768][512] fp8
    const size_t KB_OFF = QB_OFF + (size_t)NROWS * 256;    // (in ushort units)
    const size_t PT_OFF = KB_OFF + (size_t)NROWS * 256;    // [32768][2048] fp8
    const size_t END_USH = PT_OFF + (size_t)B_ * S_ * 1024;
    float* lpart    = (float*)(ws + END_USH);              // [16][4][2048] fp32
    float* wred     = lpart + (size_t)B_ * 4 * 2048;       // [16][8][2048] fp32
    float* xw_parts = wred + (size_t)B_ * 8 * 2048;        // [16][16][512] fp32
    const size_t need = END_USH * 2
                      + ((size_t)B_ * 4 * 2048 + (size_t)B_ * 8 * 2048
                         + (size_t)B_ * 16 * F_) * 4;
    if (ws_size < need) return;

    unsigned short* xb = ws + XB_OFF;
    unsigned short* Wt = ws + WT_OFF;
    unsigned char*  Qb8 = (unsigned char*)(ws + QB_OFF);
    unsigned char*  Kb8 = (unsigned char*)(ws + KB_OFF);
    unsigned char*  pt  = (unsigned char*)(ws + PT_OFF);

    conv_xw<<<2560, 256, 0, stream>>>(x, Wq, Wk, xb, Wt);
    qk_gemm<<<2048, 256, 0, stream>>>(xb, Wt, Qb8, Kb8);
    attn_w<<<1024, 256, 0, stream>>>(Qb8, Kb8, pt, lpart);
    w_red<<<2048, 256, 0, stream>>>(pt, lpart, wred);
    xw_part<<<256, 256, 0, stream>>>(x, wred, xw_parts);
    final_out<<<B_, 512, 0, stream>>>(xw_parts, Wv, out);
}

// Round 24
// 182.511 us; speedup vs baseline: 1.1447x; 1.1447x over previous
//
#include <hip/hip_runtime.h>

typedef short bf16x8 __attribute__((ext_vector_type(8)));
typedef float f32x4 __attribute__((ext_vector_type(4)));
typedef unsigned short us4 __attribute__((ext_vector_type(4)));

#define B_ 16
#define S_ 2048
#define F_ 512
#define U_ 512
#define NROWS (B_ * S_)          // 32768

#define MFMA(a, b, c)  __builtin_amdgcn_mfma_f32_16x16x32_bf16((a), (b), (c), 0, 0, 0)
#define MFMA8(a, b, c) __builtin_amdgcn_mfma_f32_16x16x32_fp8_fp8((a), (b), (c), 0, 0, 0)

// async global->LDS, 16B per lane; LDS dest = uniform base + lane*16
#define GL16(g, s) __builtin_amdgcn_global_load_lds( \
    (const __attribute__((address_space(1))) unsigned int*)(g), \
    (__attribute__((address_space(3))) unsigned int*)(s), 16, 0, 0)

__device__ __forceinline__ unsigned short f2b(float f) {
    unsigned u = __builtin_bit_cast(unsigned, f);
    return (unsigned short)((u + 0x7FFFu + ((u >> 16) & 1u)) >> 16);
}
__device__ __forceinline__ float b2f(unsigned short s) {
    return __builtin_bit_cast(float, (unsigned)s << 16);
}

// ---------------------------------------------------------------------------
// Fused converts: blocks 0..2047 convert x fp32->bf16; blocks 2048..2559
// transpose W_q/W_k fp32 -> Wt bf16 [z][n][k].
// ---------------------------------------------------------------------------
__global__ __launch_bounds__(256) void conv_xw(
    const float* __restrict__ x,
    const float* __restrict__ Wq,
    const float* __restrict__ Wk,
    unsigned short* __restrict__ xb,
    unsigned short* __restrict__ Wt)
{
    const int d = blockIdx.x;
    if (d < 2048) {
        const size_t n8 = (size_t)NROWS * F_ / 8;
        const size_t stride = (size_t)2048 * 256;
        for (size_t i = (size_t)d * 256 + threadIdx.x; i < n8; i += stride) {
            const float4 a = ((const float4*)x)[i * 2];
            const float4 b = ((const float4*)x)[i * 2 + 1];
            us4 lo, hi;
            lo.x = f2b(a.x); lo.y = f2b(a.y); lo.z = f2b(a.z); lo.w = f2b(a.w);
            hi.x = f2b(b.x); hi.y = f2b(b.y); hi.z = f2b(b.z); hi.w = f2b(b.w);
            ((us4*)xb)[i * 2]     = lo;
            ((us4*)xb)[i * 2 + 1] = hi;
        }
    } else {
        __shared__ float tile[32][33];
        const int idx = d - 2048;              // 0..511
        const int z = idx >> 8, rem = idx & 255;
        const int k0 = (rem >> 4) * 32, n0 = (rem & 15) * 32;
        const float* W = (z == 0) ? Wq : Wk;
        unsigned short* out = Wt + (size_t)z * F_ * U_;
        const int r = threadIdx.x >> 5, c = threadIdx.x & 31;
        #pragma unroll
        for (int p = 0; p < 4; ++p)
            tile[p * 8 + r][c] = W[(size_t)(k0 + p * 8 + r) * U_ + n0 + c];
        __syncthreads();
        #pragma unroll
        for (int p = 0; p < 4; ++p)
            out[(size_t)(n0 + p * 8 + r) * F_ + k0 + c] = f2b(tile[c][p * 8 + r]);
    }
}

// ---------------------------------------------------------------------------
// Q/K GEMM v5: BN=128, reg-prefetch dbuf, one barrier/kc, XCD-chunked.
// Outputs FP8 E4M3, UNSCALED: Qb8 linear; Kb8 with per-row unit swizzle
// (unit ^= row&31).  2048 blocks.
// ---------------------------------------------------------------------------
__global__ __launch_bounds__(256) void qk_gemm(
    const unsigned short* __restrict__ xb,
    const unsigned short* __restrict__ Wt,
    unsigned char* __restrict__ Qb8,
    unsigned char* __restrict__ Kb8)
{
    __shared__ char smem[128 * 65 * 4];                 // 33280 B
    unsigned short* Xs0 = (unsigned short*)smem;        // [128][32]
    unsigned short* Ws0 = Xs0 + 128 * 32;               // [128][32]
    unsigned short* Xs1 = Ws0 + 128 * 32;
    unsigned short* Ws1 = Xs1 + 128 * 32;               // 32 KB dbuf
    float* Cs = (float*)smem;                           // [128][65] epilogue

    const int dd = blockIdx.x;                 // 0..2047
    const int gi = (dd & 7) * 256 + (dd >> 3); // contiguous 256 per XCD
    const int mtile = gi >> 3;                 // 0..255
    const int sub = gi & 7;
    const int z = sub >> 2;                    // 0..1
    const int bm = mtile * 128;
    const int bn = (sub & 3) * 128;

    const unsigned short* Wz = Wt + (size_t)z * F_ * U_;
    const int t = threadIdx.x;
    const int w = t >> 6, l = t & 63, lr = l & 15, lg = l >> 4;
    const int vxA = (lr >> 1) & 3;             // read-side slot XOR

    const int row0 = t >> 2,         slot0 = t & 3;     // rows 0..63
    const int row1 = (256 + t) >> 2, slot1 = t & 3;     // rows 64..127

    f32x4 acc[2][8];
    #pragma unroll
    for (int mt = 0; mt < 2; ++mt)
        #pragma unroll
        for (int nt = 0; nt < 8; ++nt)
            acc[mt][nt] = (f32x4){0.f, 0.f, 0.f, 0.f};

    bf16x8 xr0, xr1, wr0, wr1;
    xr0 = *(const bf16x8*)&xb[(size_t)(bm + row0) * F_ + slot0 * 8];
    xr1 = *(const bf16x8*)&xb[(size_t)(bm + row1) * F_ + slot1 * 8];
    wr0 = *(const bf16x8*)&Wz[(size_t)(bn + row0) * F_ + slot0 * 8];
    wr1 = *(const bf16x8*)&Wz[(size_t)(bn + row1) * F_ + slot1 * 8];
    *(bf16x8*)&Xs0[row0 * 32 + ((slot0 ^ ((row0 >> 1) & 3)) * 8)] = xr0;
    *(bf16x8*)&Xs0[row1 * 32 + ((slot1 ^ ((row1 >> 1) & 3)) * 8)] = xr1;
    *(bf16x8*)&Ws0[row0 * 32 + ((slot0 ^ ((row0 >> 1) & 3)) * 8)] = wr0;
    *(bf16x8*)&Ws0[row1 * 32 + ((slot1 ^ ((row1 >> 1) & 3)) * 8)] = wr1;
    xr0 = *(const bf16x8*)&xb[(size_t)(bm + row0) * F_ + 32 + slot0 * 8];
    xr1 = *(const bf16x8*)&xb[(size_t)(bm + row1) * F_ + 32 + slot1 * 8];
    wr0 = *(const bf16x8*)&Wz[(size_t)(bn + row0) * F_ + 32 + slot0 * 8];
    wr1 = *(const bf16x8*)&Wz[(size_t)(bn + row1) * F_ + 32 + slot1 * 8];
    __syncthreads();

    int cur = 0;
    for (int kc = 0; kc < 16; ++kc) {
        unsigned short* Xc = cur ? Xs1 : Xs0;
        unsigned short* Wc = cur ? Ws1 : Ws0;
        if (kc < 15) {
            unsigned short* Xn = cur ? Xs0 : Xs1;
            unsigned short* Wn = cur ? Ws0 : Ws1;
            *(bf16x8*)&Xn[row0 * 32 + ((slot0 ^ ((row0 >> 1) & 3)) * 8)] = xr0;
            *(bf16x8*)&Xn[row1 * 32 + ((slot1 ^ ((row1 >> 1) & 3)) * 8)] = xr1;
            *(bf16x8*)&Wn[row0 * 32 + ((slot0 ^ ((row0 >> 1) & 3)) * 8)] = wr0;
            *(bf16x8*)&Wn[row1 * 32 + ((slot1 ^ ((row1 >> 1) & 3)) * 8)] = wr1;
            const int k2 = ((kc + 2 < 16) ? kc + 2 : 15) * 32;
            xr0 = *(const bf16x8*)&xb[(size_t)(bm + row0) * F_ + k2 + slot0 * 8];
            xr1 = *(const bf16x8*)&xb[(size_t)(bm + row1) * F_ + k2 + slot1 * 8];
            wr0 = *(const bf16x8*)&Wz[(size_t)(bn + row0) * F_ + k2 + slot0 * 8];
            wr1 = *(const bf16x8*)&Wz[(size_t)(bn + row1) * F_ + k2 + slot1 * 8];
        }
        const bf16x8 a0 = *(const bf16x8*)&Xc[(w * 32 + lr) * 32 + ((lg ^ vxA) * 8)];
        const bf16x8 a1 = *(const bf16x8*)&Xc[(w * 32 + 16 + lr) * 32 + ((lg ^ vxA) * 8)];
        #pragma unroll
        for (int nt = 0; nt < 8; ++nt) {
            const bf16x8 bb = *(const bf16x8*)&Wc[(nt * 16 + lr) * 32 + ((lg ^ vxA) * 8)];
            acc[0][nt] = MFMA(a0, bb, acc[0][nt]);
            acc[1][nt] = MFMA(a1, bb, acc[1][nt]);
        }
        __syncthreads();
        cur ^= 1;
    }

    unsigned char* out8 = (z == 0) ? Qb8 : Kb8;
    #pragma unroll
    for (int p = 0; p < 2; ++p) {
        if (p) __syncthreads();
        #pragma unroll
        for (int mt = 0; mt < 2; ++mt)
            #pragma unroll
            for (int nt = 0; nt < 4; ++nt)
                #pragma unroll
                for (int j = 0; j < 4; ++j)
                    Cs[(w * 32 + mt * 16 + lg * 4 + j) * 65 + nt * 16 + lr]
                        = acc[mt][p * 4 + nt][j];
        __syncthreads();
        const int row = t >> 1, half = t & 1;
        const int rr = row & 31;
        #pragma unroll
        for (int v = 0; v < 4; ++v) {
            const float* c = &Cs[row * 65 + half * 32 + v * 8];
            int lo = __builtin_amdgcn_cvt_pk_fp8_f32(c[0], c[1], 0, false);
            lo     = __builtin_amdgcn_cvt_pk_fp8_f32(c[2], c[3], lo, true);
            int hi = __builtin_amdgcn_cvt_pk_fp8_f32(c[4], c[5], 0, false);
            hi     = __builtin_amdgcn_cvt_pk_fp8_f32(c[6], c[7], hi, true);
            const int u  = (bn >> 3) + p * 8 + half * 4 + v;  // 8B unit 0..63
            const int pu = (z == 0) ? u : (u ^ rr);           // K: row swizzle
            unsigned* dst = (unsigned*)&out8[(size_t)(bm + row) * 512 + pu * 8];
            dst[0] = (unsigned)lo;
            dst[1] = (unsigned)hi;
        }
    }
}

// ---------------------------------------------------------------------------
// attn_w v8 (R22-proven): fp8 Q/K QK^T, half-split (512 blocks (b,qblk,h),
// 2 blocks/CU), one barrier/iter, m==0 softmax via exp2 (scale folded into
// the log2e constant), p~ stored fp8.  K rows linear-DMA'd; data
// pre-swizzled (unit^row&31) by qk_gemm.
// ---------------------------------------------------------------------------
__global__ __launch_bounds__(256, 2) void attn_w(
    const unsigned char* __restrict__ Qb8,
    const unsigned char* __restrict__ Kb8,
    unsigned char* __restrict__ ptil,              // [32768 q][2048 k] fp8
    float* __restrict__ lpart)                     // [16][2][2048]
{
    __shared__ unsigned char Ks8[2][32 * 512];     // 32.0 KB
    __shared__ unsigned char Ps8[128 * 48];        //  6.0 KB

    const int d = blockIdx.x;                      // 0..511
    const int b    = ((d & 7) << 1) | (d >> 8);    // XCD j -> batches 2j,2j+1
    const int qblk = (d >> 3) & 15;                // 0..15
    const int h    = (d >> 7) & 1;                 // key-half
    const int t = threadIdx.x;                     // 0..255
    const int qs = t >> 6;                         // q-wave 0..3
    const int l = t & 63, lr = l & 15, lg = l >> 4;
    const float sc2 = 0.06375873f;                 // log2(e)/sqrt(512)

    // ---- Q fragments (fp8, 8B per kc-chunk) for the wave's 32 queries ----
    long qA[16], qB[16];
    {
        const unsigned char* qg =
            Qb8 + (size_t)(b * S_ + qblk * 128 + qs * 32 + lr) * 512 + lg * 8;
        #pragma unroll
        for (int kc = 0; kc < 16; ++kc) {
            qA[kc] = *(const long*)(qg + kc * 32);
            qB[kc] = *(const long*)(qg + 16 * 512 + kc * 32);
        }
    }

    const unsigned char* kgb = Kb8 + (size_t)b * S_ * 512 + (size_t)h * 1024 * 512;
    unsigned char* pbase = ptil + ((size_t)(b * 16 + qblk) * 128) * 2048 + h * 1024;

    // wave qs stages rows qs*8..qs*8+7 (4 ops x 1 KB = 2 rows each)
    #define STAGE(it_, buf_)                                                     \
    do {                                                                         \
        const unsigned char* ksrc_ = kgb + ((size_t)(it_) * 32) * 512;           \
        _Pragma("unroll")                                                        \
        for (int i_ = 0; i_ < 4; ++i_) {                                         \
            const int r_ = qs * 8 + i_ * 2;                                      \
            GL16(ksrc_ + (size_t)r_ * 512 + l * 16, &Ks8[buf_][r_ * 512]);       \
        }                                                                        \
    } while (0)

    STAGE(0, 0);
    __syncthreads();

    float l0 = 0.f, l1 = 0.f;
    int cur = 0;

    for (int it = 0; it < 32; ++it) {
        const int nt = (it + 1 < 32) ? it + 1 : it;
        STAGE(nt, cur ^ 1);

        f32x4 sA0 = (f32x4){0.f,0.f,0.f,0.f};
        f32x4 sA1 = (f32x4){0.f,0.f,0.f,0.f};
        f32x4 sB0 = (f32x4){0.f,0.f,0.f,0.f};
        f32x4 sB1 = (f32x4){0.f,0.f,0.f,0.f};
        #pragma unroll
        for (int kc = 0; kc < 16; ++kc) {
            const int u = kc * 4 + lg;
            const long k0 = *(const long*)&Ks8[cur][lr * 512 + ((u ^ lr) * 8)];
            const long k1 = *(const long*)&Ks8[cur][(16 + lr) * 512 + ((u ^ (16 + lr)) * 8)];
            sA0 = MFMA8(k0, qA[kc], sA0);
            sA1 = MFMA8(k1, qA[kc], sA1);
            sB0 = MFMA8(k0, qB[kc], sB0);
            sB1 = MFMA8(k1, qB[kc], sB1);
        }

        float eA0[4], eA1[4], eB0[4], eB1[4];
        float sum0 = 0.f, sum1 = 0.f;
        #pragma unroll
        for (int j = 0; j < 4; ++j) {
            eA0[j] = exp2f(sA0[j] * sc2); eA1[j] = exp2f(sA1[j] * sc2);
            eB0[j] = exp2f(sB0[j] * sc2); eB1[j] = exp2f(sB1[j] * sc2);
            sum0 += eA0[j] + eA1[j];
            sum1 += eB0[j] + eB1[j];
        }
        sum0 += __shfl_xor(sum0, 16); sum0 += __shfl_xor(sum0, 32);
        sum1 += __shfl_xor(sum1, 16); sum1 += __shfl_xor(sum1, 32);
        l0 += sum0; l1 += sum1;

        // ---- pack p~ to fp8, deposit into wave-private LDS strip ----
        int dA0 = __builtin_amdgcn_cvt_pk_fp8_f32(eA0[0], eA0[1], 0, false);
        dA0     = __builtin_amdgcn_cvt_pk_fp8_f32(eA0[2], eA0[3], dA0, true);
        int dA1 = __builtin_amdgcn_cvt_pk_fp8_f32(eA1[0], eA1[1], 0, false);
        dA1     = __builtin_amdgcn_cvt_pk_fp8_f32(eA1[2], eA1[3], dA1, true);
        int dB0 = __builtin_amdgcn_cvt_pk_fp8_f32(eB0[0], eB0[1], 0, false);
        dB0     = __builtin_amdgcn_cvt_pk_fp8_f32(eB0[2], eB0[3], dB0, true);
        int dB1 = __builtin_amdgcn_cvt_pk_fp8_f32(eB1[0], eB1[1], 0, false);
        dB1     = __builtin_amdgcn_cvt_pk_fp8_f32(eB1[2], eB1[3], dB1, true);
        unsigned* Pu = (unsigned*)Ps8;
        Pu[(qs * 32 + lr) * 12 + lg]          = (unsigned)dA0;
        Pu[(qs * 32 + lr) * 12 + 4 + lg]      = (unsigned)dA1;
        Pu[(qs * 32 + 16 + lr) * 12 + lg]     = (unsigned)dB0;
        Pu[(qs * 32 + 16 + lr) * 12 + 4 + lg] = (unsigned)dB1;

        // ---- wave-local copy-out (32 rows x 32B per wave) ----
        {
            const int rl = l >> 1, seg = l & 1;
            const int row = qs * 32 + rl;
            *(bf16x8*)&pbase[(size_t)row * 2048 + it * 32 + seg * 16]
                = *(const bf16x8*)&Ps8[row * 48 + seg * 16];
        }

        __syncthreads();                           // K dbuf swap + DMA drain
        cur ^= 1;
    }

    if (lg == 0) {
        lpart[((size_t)b * 2 + h) * 2048 + qblk * 128 + qs * 32 + lr]      = l0;
        lpart[((size_t)b * 2 + h) * 2048 + qblk * 128 + qs * 32 + 16 + lr] = l1;
    }
    #undef STAGE
}

// ---------------------------------------------------------------------------
// w_red: 2048 blocks (b, qsl, kc).  Reads fp8 p~, decodes with HW cvt.
// wred[b][qsl][kc*128+j] = sum_q p~[q][kc*128+j] / (l0[q]+l1[q]).
// ---------------------------------------------------------------------------
__global__ __launch_bounds__(256) void w_red(
    const unsigned char* __restrict__ ptil,
    const float* __restrict__ lpart,               // [16][2][2048]
    float* __restrict__ wred)                      // [16][8][2048]
{
    const int d = blockIdx.x;                      // 0..2047
    const int b = d >> 7, qsl = (d >> 4) & 7, kc = d & 15;
    const int t = threadIdx.x;
    __shared__ float linv[256];
    __shared__ float wsum[8][132];

    if (t < 256) {
        const float a = lpart[((size_t)b * 2 + 0) * 2048 + qsl * 256 + t];
        const float c = lpart[((size_t)b * 2 + 1) * 2048 + qsl * 256 + t];
        linv[t] = 1.f / (a + c);
    }
    __syncthreads();

    const int kk = (t & 31) * 4, qp = t >> 5;      // 32 k-slots x 8 q-parallel
    float a0 = 0.f, a1 = 0.f, a2 = 0.f, a3 = 0.f;
    const unsigned char* pb = ptil + (size_t)b * 2048 * 2048
                            + (size_t)(qsl * 256) * 2048 + kc * 128 + kk;
    #pragma unroll 4
    for (int qq = qp; qq < 256; qq += 8) {
        const int v = *(const int*)&pb[(size_t)qq * 2048];
        const float li = linv[qq];
        a0 += __builtin_amdgcn_cvt_f32_fp8(v, 0) * li;
        a1 += __builtin_amdgcn_cvt_f32_fp8(v, 1) * li;
        a2 += __builtin_amdgcn_cvt_f32_fp8(v, 2) * li;
        a3 += __builtin_amdgcn_cvt_f32_fp8(v, 3) * li;
    }
    wsum[qp][kk + 0] = a0; wsum[qp][kk + 1] = a1;
    wsum[qp][kk + 2] = a2; wsum[qp][kk + 3] = a3;
    __syncthreads();
    if (t < 128) {
        float s = 0.f;
        #pragma unroll
        for (int p = 0; p < 8; ++p) s += wsum[p][t];
        wred[((size_t)(b * 8 + qsl)) * 2048 + kc * 128 + t] = s;
    }
}

// ---------------------------------------------------------------------------
// xw_part: block (b, kc).  wk from wred partials, then
// phase B (fp32 x): xw[f] = sum_k wk * x[b][k][f].
// ---------------------------------------------------------------------------
__global__ __launch_bounds__(256) void xw_part(
    const float* __restrict__ x,
    const float* __restrict__ wred,                // [16][8][2048]
    float* __restrict__ xw_out)                    // [16][16][512]
{
    const int b = blockIdx.x >> 4, kc = blockIdx.x & 15;
    const int t = threadIdx.x;
    __shared__ float wk[128];

    if (t < 128) {
        float s = 0.f;
        #pragma unroll
        for (int p = 0; p < 8; ++p)
            s += wred[((size_t)(b * 8 + p)) * 2048 + kc * 128 + t];
        wk[t] = s;
    }
    __syncthreads();

    const float* xp = x + ((size_t)(b * S_ + kc * 128)) * F_ + t * 2;
    float2 acc = {0.f, 0.f};
    #pragma unroll 8
    for (int k = 0; k < 128; ++k) {
        const float2 v = *(const float2*)(xp + (size_t)k * F_);
        acc.x += wk[k] * v.x;
        acc.y += wk[k] * v.y;
    }
    float* o = xw_out + (size_t)(b * 16 + kc) * F_ + t * 2;
    o[0] = acc.x; o[1] = acc.y;
}

// ---------------------------------------------------------------------------
// final: out[b][u] = (1/2048) * sum_f xw[b][f] * Wv[f][u]   (fp32)
// ---------------------------------------------------------------------------
__global__ __launch_bounds__(512) void final_out(
    const float* __restrict__ xw_parts,            // [16][16][512]
    const float* __restrict__ Wv,
    float* __restrict__ out)
{
    const int b = blockIdx.x, t = threadIdx.x;     // 512 threads = u
    __shared__ float xw[512];
    float s = 0.f;
    #pragma unroll
    for (int p = 0; p < 16; ++p)
        s += xw_parts[(size_t)(b * 16 + p) * F_ + t];
    xw[t] = s;
    __syncthreads();
    float acc = 0.f;
    #pragma unroll 8
    for (int f = 0; f < F_; ++f)
        acc += xw[f] * Wv[(size_t)f * U_ + t];
    out[(size_t)b * U_ + t] = acc * (1.0f / (float)S_);
}

extern "C" void kernel_launch(void* const* d_in, const int* in_sizes, int n_in,
                              void* d_out, int out_size, void* d_ws, size_t ws_size,
                              hipStream_t stream)
{
    const float* x  = (const float*)d_in[0];
    const float* Wq = (const float*)d_in[1];
    const float* Wk = (const float*)d_in[2];
    const float* Wv = (const float*)d_in[3];
    float* out = (float*)d_out;

    unsigned short* ws = (unsigned short*)d_ws;
    const size_t XB_OFF = 0;                               // [32768][512] bf16
    const size_t WT_OFF = XB_OFF + (size_t)NROWS * F_;     // 2x[512][512] bf16
    const size_t QB_OFF = WT_OFF + 2ull * F_ * U_;         // [32768][512] fp8
    const size_t KB_OFF = QB_OFF + (size_t)NROWS * 256;    // (in ushort units)
    const size_t PT_OFF = KB_OFF + (size_t)NROWS * 256;    // [32768][2048] fp8
    const size_t END_USH = PT_OFF + (size_t)B_ * S_ * 1024;
    float* lpart    = (float*)(ws + END_USH);              // [16][2][2048] fp32
    float* wred     = lpart + (size_t)B_ * 2 * 2048;       // [16][8][2048] fp32
    float* xw_parts = wred + (size_t)B_ * 8 * 2048;        // [16][16][512] fp32
    const size_t need = END_USH * 2
                      + ((size_t)B_ * 2 * 2048 + (size_t)B_ * 8 * 2048
                         + (size_t)B_ * 16 * F_) * 4;
    if (ws_size < need) return;

    unsigned short* xb = ws + XB_OFF;
    unsigned short* Wt = ws + WT_OFF;
    unsigned char*  Qb8 = (unsigned char*)(ws + QB_OFF);
    unsigned char*  Kb8 = (unsigned char*)(ws + KB_OFF);
    unsigned char*  pt  = (unsigned char*)(ws + PT_OFF);

    conv_xw<<<2560, 256, 0, stream>>>(x, Wq, Wk, xb, Wt);
    qk_gemm<<<2048, 256, 0, stream>>>(xb, Wt, Qb8, Kb8);
    attn_w<<<512, 256, 0, stream>>>(Qb8, Kb8, pt, lpart);
    w_red<<<2048, 256, 0, stream>>>(pt, lpart, wred);
    xw_part<<<256, 256, 0, stream>>>(x, wred, xw_parts);
    final_out<<<B_, 512, 0, stream>>>(xw_parts, Wv, out);
}

// Round 25
// 178.833 us; speedup vs baseline: 1.1682x; 1.0206x over previous
//
#include <hip/hip_runtime.h>

typedef short bf16x8 __attribute__((ext_vector_type(8)));
typedef float f32x4 __attribute__((ext_vector_type(4)));
typedef unsigned short us4 __attribute__((ext_vector_type(4)));

#define B_ 16
#define S_ 2048
#define F_ 512
#define U_ 512
#define NROWS (B_ * S_)          // 32768

#define MFMA(a, b, c)  __builtin_amdgcn_mfma_f32_16x16x32_bf16((a), (b), (c), 0, 0, 0)
#define MFMA8(a, b, c) __builtin_amdgcn_mfma_f32_16x16x32_fp8_fp8((a), (b), (c), 0, 0, 0)

// async global->LDS, 16B per lane; LDS dest = uniform base + lane*16
#define GL16(g, s) __builtin_amdgcn_global_load_lds( \
    (const __attribute__((address_space(1))) unsigned int*)(g), \
    (__attribute__((address_space(3))) unsigned int*)(s), 16, 0, 0)

__device__ __forceinline__ unsigned short f2b(float f) {
    unsigned u = __builtin_bit_cast(unsigned, f);
    return (unsigned short)((u + 0x7FFFu + ((u >> 16) & 1u)) >> 16);
}
__device__ __forceinline__ float b2f(unsigned short s) {
    return __builtin_bit_cast(float, (unsigned)s << 16);
}

// ---------------------------------------------------------------------------
// Fused converts: blocks 0..2047 convert x fp32->bf16; blocks 2048..2559
// transpose W_q/W_k fp32 -> Wt bf16 [z][n][k].
// ---------------------------------------------------------------------------
__global__ __launch_bounds__(256) void conv_xw(
    const float* __restrict__ x,
    const float* __restrict__ Wq,
    const float* __restrict__ Wk,
    unsigned short* __restrict__ xb,
    unsigned short* __restrict__ Wt)
{
    const int d = blockIdx.x;
    if (d < 2048) {
        const size_t n8 = (size_t)NROWS * F_ / 8;
        const size_t stride = (size_t)2048 * 256;
        for (size_t i = (size_t)d * 256 + threadIdx.x; i < n8; i += stride) {
            const float4 a = ((const float4*)x)[i * 2];
            const float4 b = ((const float4*)x)[i * 2 + 1];
            us4 lo, hi;
            lo.x = f2b(a.x); lo.y = f2b(a.y); lo.z = f2b(a.z); lo.w = f2b(a.w);
            hi.x = f2b(b.x); hi.y = f2b(b.y); hi.z = f2b(b.z); hi.w = f2b(b.w);
            ((us4*)xb)[i * 2]     = lo;
            ((us4*)xb)[i * 2 + 1] = hi;
        }
    } else {
        __shared__ float tile[32][33];
        const int idx = d - 2048;              // 0..511
        const int z = idx >> 8, rem = idx & 255;
        const int k0 = (rem >> 4) * 32, n0 = (rem & 15) * 32;
        const float* W = (z == 0) ? Wq : Wk;
        unsigned short* out = Wt + (size_t)z * F_ * U_;
        const int r = threadIdx.x >> 5, c = threadIdx.x & 31;
        #pragma unroll
        for (int p = 0; p < 4; ++p)
            tile[p * 8 + r][c] = W[(size_t)(k0 + p * 8 + r) * U_ + n0 + c];
        __syncthreads();
        #pragma unroll
        for (int p = 0; p < 4; ++p)
            out[(size_t)(n0 + p * 8 + r) * F_ + k0 + c] = f2b(tile[c][p * 8 + r]);
    }
}

// ---------------------------------------------------------------------------
// Q/K GEMM v5: BN=128, reg-prefetch dbuf, one barrier/kc, XCD-chunked.
// Outputs FP8 E4M3, UNSCALED: Qb8 linear; Kb8 with per-row unit swizzle
// (unit ^= row&31).  2048 blocks.
// ---------------------------------------------------------------------------
__global__ __launch_bounds__(256) void qk_gemm(
    const unsigned short* __restrict__ xb,
    const unsigned short* __restrict__ Wt,
    unsigned char* __restrict__ Qb8,
    unsigned char* __restrict__ Kb8)
{
    __shared__ char smem[128 * 65 * 4];                 // 33280 B
    unsigned short* Xs0 = (unsigned short*)smem;        // [128][32]
    unsigned short* Ws0 = Xs0 + 128 * 32;               // [128][32]
    unsigned short* Xs1 = Ws0 + 128 * 32;
    unsigned short* Ws1 = Xs1 + 128 * 32;               // 32 KB dbuf
    float* Cs = (float*)smem;                           // [128][65] epilogue

    const int dd = blockIdx.x;                 // 0..2047
    const int gi = (dd & 7) * 256 + (dd >> 3); // contiguous 256 per XCD
    const int mtile = gi >> 3;                 // 0..255
    const int sub = gi & 7;
    const int z = sub >> 2;                    // 0..1
    const int bm = mtile * 128;
    const int bn = (sub & 3) * 128;

    const unsigned short* Wz = Wt + (size_t)z * F_ * U_;
    const int t = threadIdx.x;
    const int w = t >> 6, l = t & 63, lr = l & 15, lg = l >> 4;
    const int vxA = (lr >> 1) & 3;             // read-side slot XOR

    const int row0 = t >> 2,         slot0 = t & 3;     // rows 0..63
    const int row1 = (256 + t) >> 2, slot1 = t & 3;     // rows 64..127

    f32x4 acc[2][8];
    #pragma unroll
    for (int mt = 0; mt < 2; ++mt)
        #pragma unroll
        for (int nt = 0; nt < 8; ++nt)
            acc[mt][nt] = (f32x4){0.f, 0.f, 0.f, 0.f};

    bf16x8 xr0, xr1, wr0, wr1;
    xr0 = *(const bf16x8*)&xb[(size_t)(bm + row0) * F_ + slot0 * 8];
    xr1 = *(const bf16x8*)&xb[(size_t)(bm + row1) * F_ + slot1 * 8];
    wr0 = *(const bf16x8*)&Wz[(size_t)(bn + row0) * F_ + slot0 * 8];
    wr1 = *(const bf16x8*)&Wz[(size_t)(bn + row1) * F_ + slot1 * 8];
    *(bf16x8*)&Xs0[row0 * 32 + ((slot0 ^ ((row0 >> 1) & 3)) * 8)] = xr0;
    *(bf16x8*)&Xs0[row1 * 32 + ((slot1 ^ ((row1 >> 1) & 3)) * 8)] = xr1;
    *(bf16x8*)&Ws0[row0 * 32 + ((slot0 ^ ((row0 >> 1) & 3)) * 8)] = wr0;
    *(bf16x8*)&Ws0[row1 * 32 + ((slot1 ^ ((row1 >> 1) & 3)) * 8)] = wr1;
    xr0 = *(const bf16x8*)&xb[(size_t)(bm + row0) * F_ + 32 + slot0 * 8];
    xr1 = *(const bf16x8*)&xb[(size_t)(bm + row1) * F_ + 32 + slot1 * 8];
    wr0 = *(const bf16x8*)&Wz[(size_t)(bn + row0) * F_ + 32 + slot0 * 8];
    wr1 = *(const bf16x8*)&Wz[(size_t)(bn + row1) * F_ + 32 + slot1 * 8];
    __syncthreads();

    int cur = 0;
    for (int kc = 0; kc < 16; ++kc) {
        unsigned short* Xc = cur ? Xs1 : Xs0;
        unsigned short* Wc = cur ? Ws1 : Ws0;
        if (kc < 15) {
            unsigned short* Xn = cur ? Xs0 : Xs1;
            unsigned short* Wn = cur ? Ws0 : Ws1;
            *(bf16x8*)&Xn[row0 * 32 + ((slot0 ^ ((row0 >> 1) & 3)) * 8)] = xr0;
            *(bf16x8*)&Xn[row1 * 32 + ((slot1 ^ ((row1 >> 1) & 3)) * 8)] = xr1;
            *(bf16x8*)&Wn[row0 * 32 + ((slot0 ^ ((row0 >> 1) & 3)) * 8)] = wr0;
            *(bf16x8*)&Wn[row1 * 32 + ((slot1 ^ ((row1 >> 1) & 3)) * 8)] = wr1;
            const int k2 = ((kc + 2 < 16) ? kc + 2 : 15) * 32;
            xr0 = *(const bf16x8*)&xb[(size_t)(bm + row0) * F_ + k2 + slot0 * 8];
            xr1 = *(const bf16x8*)&xb[(size_t)(bm + row1) * F_ + k2 + slot1 * 8];
            wr0 = *(const bf16x8*)&Wz[(size_t)(bn + row0) * F_ + k2 + slot0 * 8];
            wr1 = *(const bf16x8*)&Wz[(size_t)(bn + row1) * F_ + k2 + slot1 * 8];
        }
        const bf16x8 a0 = *(const bf16x8*)&Xc[(w * 32 + lr) * 32 + ((lg ^ vxA) * 8)];
        const bf16x8 a1 = *(const bf16x8*)&Xc[(w * 32 + 16 + lr) * 32 + ((lg ^ vxA) * 8)];
        #pragma unroll
        for (int nt = 0; nt < 8; ++nt) {
            const bf16x8 bb = *(const bf16x8*)&Wc[(nt * 16 + lr) * 32 + ((lg ^ vxA) * 8)];
            acc[0][nt] = MFMA(a0, bb, acc[0][nt]);
            acc[1][nt] = MFMA(a1, bb, acc[1][nt]);
        }
        __syncthreads();
        cur ^= 1;
    }

    unsigned char* out8 = (z == 0) ? Qb8 : Kb8;
    #pragma unroll
    for (int p = 0; p < 2; ++p) {
        if (p) __syncthreads();
        #pragma unroll
        for (int mt = 0; mt < 2; ++mt)
            #pragma unroll
            for (int nt = 0; nt < 4; ++nt)
                #pragma unroll
                for (int j = 0; j < 4; ++j)
                    Cs[(w * 32 + mt * 16 + lg * 4 + j) * 65 + nt * 16 + lr]
                        = acc[mt][p * 4 + nt][j];
        __syncthreads();
        const int row = t >> 1, half = t & 1;
        const int rr = row & 31;
        #pragma unroll
        for (int v = 0; v < 4; ++v) {
            const float* c = &Cs[row * 65 + half * 32 + v * 8];
            int lo = __builtin_amdgcn_cvt_pk_fp8_f32(c[0], c[1], 0, false);
            lo     = __builtin_amdgcn_cvt_pk_fp8_f32(c[2], c[3], lo, true);
            int hi = __builtin_amdgcn_cvt_pk_fp8_f32(c[4], c[5], 0, false);
            hi     = __builtin_amdgcn_cvt_pk_fp8_f32(c[6], c[7], hi, true);
            const int u  = (bn >> 3) + p * 8 + half * 4 + v;  // 8B unit 0..63
            const int pu = (z == 0) ? u : (u ^ rr);           // K: row swizzle
            unsigned* dst = (unsigned*)&out8[(size_t)(bm + row) * 512 + pu * 8];
            dst[0] = (unsigned)lo;
            dst[1] = (unsigned)hi;
        }
    }
}

// ---------------------------------------------------------------------------
// attn_w v8 (R22-proven best): fp8 Q/K QK^T (mfma_f32_16x16x32_fp8_fp8),
// half-split (512 blocks (b,qblk,h), 2 blocks/CU), one barrier/iter,
// m==0 softmax, scores scaled by 1/sqrt(512) after MFMA, p~ stored fp8.
// K rows linear-DMA'd; data pre-swizzled (unit^row&31) by qk_gemm.
// ---------------------------------------------------------------------------
__global__ __launch_bounds__(256, 2) void attn_w(
    const unsigned char* __restrict__ Qb8,
    const unsigned char* __restrict__ Kb8,
    unsigned char* __restrict__ ptil,              // [32768 q][2048 k] fp8
    float* __restrict__ lpart)                     // [16][2][2048]
{
    __shared__ unsigned char Ks8[2][32 * 512];     // 32.0 KB
    __shared__ unsigned char Ps8[128 * 48];        //  6.0 KB

    const int d = blockIdx.x;                      // 0..511
    const int b    = ((d & 7) << 1) | (d >> 8);    // XCD j -> batches 2j,2j+1
    const int qblk = (d >> 3) & 15;                // 0..15
    const int h    = (d >> 7) & 1;                 // key-half
    const int t = threadIdx.x;                     // 0..255
    const int qs = t >> 6;                         // q-wave 0..3
    const int l = t & 63, lr = l & 15, lg = l >> 4;
    const float sc = 0.044194173824159216f;        // 1/sqrt(512)

    // ---- Q fragments (fp8, 8B per kc-chunk) for the wave's 32 queries ----
    long qA[16], qB[16];
    {
        const unsigned char* qg =
            Qb8 + (size_t)(b * S_ + qblk * 128 + qs * 32 + lr) * 512 + lg * 8;
        #pragma unroll
        for (int kc = 0; kc < 16; ++kc) {
            qA[kc] = *(const long*)(qg + kc * 32);
            qB[kc] = *(const long*)(qg + 16 * 512 + kc * 32);
        }
    }

    const unsigned char* kgb = Kb8 + (size_t)b * S_ * 512 + (size_t)h * 1024 * 512;
    unsigned char* pbase = ptil + ((size_t)(b * 16 + qblk) * 128) * 2048 + h * 1024;

    // wave qs stages rows qs*8..qs*8+7 (4 ops x 1 KB = 2 rows each)
    #define STAGE(it_, buf_)                                                     \
    do {                                                                         \
        const unsigned char* ksrc_ = kgb + ((size_t)(it_) * 32) * 512;           \
        _Pragma("unroll")                                                        \
        for (int i_ = 0; i_ < 4; ++i_) {                                         \
            const int r_ = qs * 8 + i_ * 2;                                      \
            GL16(ksrc_ + (size_t)r_ * 512 + l * 16, &Ks8[buf_][r_ * 512]);       \
        }                                                                        \
    } while (0)

    STAGE(0, 0);
    __syncthreads();

    float l0 = 0.f, l1 = 0.f;
    int cur = 0;

    for (int it = 0; it < 32; ++it) {
        const int nt = (it + 1 < 32) ? it + 1 : it;
        STAGE(nt, cur ^ 1);

        f32x4 sA0 = (f32x4){0.f,0.f,0.f,0.f};
        f32x4 sA1 = (f32x4){0.f,0.f,0.f,0.f};
        f32x4 sB0 = (f32x4){0.f,0.f,0.f,0.f};
        f32x4 sB1 = (f32x4){0.f,0.f,0.f,0.f};
        #pragma unroll
        for (int kc = 0; kc < 16; ++kc) {
            const int u = kc * 4 + lg;
            const long k0 = *(const long*)&Ks8[cur][lr * 512 + ((u ^ lr) * 8)];
            const long k1 = *(const long*)&Ks8[cur][(16 + lr) * 512 + ((u ^ (16 + lr)) * 8)];
            sA0 = MFMA8(k0, qA[kc], sA0);
            sA1 = MFMA8(k1, qA[kc], sA1);
            sB0 = MFMA8(k0, qB[kc], sB0);
            sB1 = MFMA8(k1, qB[kc], sB1);
        }

        float eA0[4], eA1[4], eB0[4], eB1[4];
        float sum0 = 0.f, sum1 = 0.f;
        #pragma unroll
        for (int j = 0; j < 4; ++j) {
            eA0[j] = __expf(sA0[j] * sc); eA1[j] = __expf(sA1[j] * sc);
            eB0[j] = __expf(sB0[j] * sc); eB1[j] = __expf(sB1[j] * sc);
            sum0 += eA0[j] + eA1[j];
            sum1 += eB0[j] + eB1[j];
        }
        sum0 += __shfl_xor(sum0, 16); sum0 += __shfl_xor(sum0, 32);
        sum1 += __shfl_xor(sum1, 16); sum1 += __shfl_xor(sum1, 32);
        l0 += sum0; l1 += sum1;

        // ---- pack p~ to fp8, deposit into wave-private LDS strip ----
        int dA0 = __builtin_amdgcn_cvt_pk_fp8_f32(eA0[0], eA0[1], 0, false);
        dA0     = __builtin_amdgcn_cvt_pk_fp8_f32(eA0[2], eA0[3], dA0, true);
        int dA1 = __builtin_amdgcn_cvt_pk_fp8_f32(eA1[0], eA1[1], 0, false);
        dA1     = __builtin_amdgcn_cvt_pk_fp8_f32(eA1[2], eA1[3], dA1, true);
        int dB0 = __builtin_amdgcn_cvt_pk_fp8_f32(eB0[0], eB0[1], 0, false);
        dB0     = __builtin_amdgcn_cvt_pk_fp8_f32(eB0[2], eB0[3], dB0, true);
        int dB1 = __builtin_amdgcn_cvt_pk_fp8_f32(eB1[0], eB1[1], 0, false);
        dB1     = __builtin_amdgcn_cvt_pk_fp8_f32(eB1[2], eB1[3], dB1, true);
        unsigned* Pu = (unsigned*)Ps8;
        Pu[(qs * 32 + lr) * 12 + lg]          = (unsigned)dA0;
        Pu[(qs * 32 + lr) * 12 + 4 + lg]      = (unsigned)dA1;
        Pu[(qs * 32 + 16 + lr) * 12 + lg]     = (unsigned)dB0;
        Pu[(qs * 32 + 16 + lr) * 12 + 4 + lg] = (unsigned)dB1;

        // ---- wave-local copy-out (32 rows x 32B per wave) ----
        {
            const int rl = l >> 1, seg = l & 1;
            const int row = qs * 32 + rl;
            *(bf16x8*)&pbase[(size_t)row * 2048 + it * 32 + seg * 16]
                = *(const bf16x8*)&Ps8[row * 48 + seg * 16];
        }

        __syncthreads();                           // K dbuf swap + DMA drain
        cur ^= 1;
    }

    if (lg == 0) {
        lpart[((size_t)b * 2 + h) * 2048 + qblk * 128 + qs * 32 + lr]      = l0;
        lpart[((size_t)b * 2 + h) * 2048 + qblk * 128 + qs * 32 + 16 + lr] = l1;
    }
    #undef STAGE
}

// ---------------------------------------------------------------------------
// w_red: 2048 blocks (b, qsl, kc).  Reads fp8 p~, decodes with HW cvt.
// wred[b][qsl][kc*128+j] = sum_q p~[q][kc*128+j] / (l0[q]+l1[q]).
// ---------------------------------------------------------------------------
__global__ __launch_bounds__(256) void w_red(
    const unsigned char* __restrict__ ptil,
    const float* __restrict__ lpart,               // [16][2][2048]
    float* __restrict__ wred)                      // [16][8][2048]
{
    const int d = blockIdx.x;                      // 0..2047
    const int b = d >> 7, qsl = (d >> 4) & 7, kc = d & 15;
    const int t = threadIdx.x;
    __shared__ float linv[256];
    __shared__ float wsum[8][132];

    if (t < 256) {
        const float a = lpart[((size_t)b * 2 + 0) * 2048 + qsl * 256 + t];
        const float c = lpart[((size_t)b * 2 + 1) * 2048 + qsl * 256 + t];
        linv[t] = 1.f / (a + c);
    }
    __syncthreads();

    const int kk = (t & 31) * 4, qp = t >> 5;      // 32 k-slots x 8 q-parallel
    float a0 = 0.f, a1 = 0.f, a2 = 0.f, a3 = 0.f;
    const unsigned char* pb = ptil + (size_t)b * 2048 * 2048
                            + (size_t)(qsl * 256) * 2048 + kc * 128 + kk;
    #pragma unroll 4
    for (int qq = qp; qq < 256; qq += 8) {
        const int v = *(const int*)&pb[(size_t)qq * 2048];
        const float li = linv[qq];
        a0 += __builtin_amdgcn_cvt_f32_fp8(v, 0) * li;
        a1 += __builtin_amdgcn_cvt_f32_fp8(v, 1) * li;
        a2 += __builtin_amdgcn_cvt_f32_fp8(v, 2) * li;
        a3 += __builtin_amdgcn_cvt_f32_fp8(v, 3) * li;
    }
    wsum[qp][kk + 0] = a0; wsum[qp][kk + 1] = a1;
    wsum[qp][kk + 2] = a2; wsum[qp][kk + 3] = a3;
    __syncthreads();
    if (t < 128) {
        float s = 0.f;
        #pragma unroll
        for (int p = 0; p < 8; ++p) s += wsum[p][t];
        wred[((size_t)(b * 8 + qsl)) * 2048 + kc * 128 + t] = s;
    }
}

// ---------------------------------------------------------------------------
// xw_part: block (b, kc).  wk from wred partials, then
// phase B (fp32 x): xw[f] = sum_k wk * x[b][k][f].
// ---------------------------------------------------------------------------
__global__ __launch_bounds__(256) void xw_part(
    const float* __restrict__ x,
    const float* __restrict__ wred,                // [16][8][2048]
    float* __restrict__ xw_out)                    // [16][16][512]
{
    const int b = blockIdx.x >> 4, kc = blockIdx.x & 15;
    const int t = threadIdx.x;
    __shared__ float wk[128];

    if (t < 128) {
        float s = 0.f;
        #pragma unroll
        for (int p = 0; p < 8; ++p)
            s += wred[((size_t)(b * 8 + p)) * 2048 + kc * 128 + t];
        wk[t] = s;
    }
    __syncthreads();

    const float* xp = x + ((size_t)(b * S_ + kc * 128)) * F_ + t * 2;
    float2 acc = {0.f, 0.f};
    #pragma unroll 8
    for (int k = 0; k < 128; ++k) {
        const float2 v = *(const float2*)(xp + (size_t)k * F_);
        acc.x += wk[k] * v.x;
        acc.y += wk[k] * v.y;
    }
    float* o = xw_out + (size_t)(b * 16 + kc) * F_ + t * 2;
    o[0] = acc.x; o[1] = acc.y;
}

// ---------------------------------------------------------------------------
// final: out[b][u] = (1/2048) * sum_f xw[b][f] * Wv[f][u]   (fp32)
// ---------------------------------------------------------------------------
__global__ __launch_bounds__(512) void final_out(
    const float* __restrict__ xw_parts,            // [16][16][512]
    const float* __restrict__ Wv,
    float* __restrict__ out)
{
    const int b = blockIdx.x, t = threadIdx.x;     // 512 threads = u
    __shared__ float xw[512];
    float s = 0.f;
    #pragma unroll
    for (int p = 0; p < 16; ++p)
        s += xw_parts[(size_t)(b * 16 + p) * F_ + t];
    xw[t] = s;
    __syncthreads();
    float acc = 0.f;
    #pragma unroll 8
    for (int f = 0; f < F_; ++f)
        acc += xw[f] * Wv[(size_t)f * U_ + t];
    out[(size_t)b * U_ + t] = acc * (1.0f / (float)S_);
}

extern "C" void kernel_launch(void* const* d_in, const int* in_sizes, int n_in,
                              void* d_out, int out_size, void* d_ws, size_t ws_size,
                              hipStream_t stream)
{
    const float* x  = (const float*)d_in[0];
    const float* Wq = (const float*)d_in[1];
    const float* Wk = (const float*)d_in[2];
    const float* Wv = (const float*)d_in[3];
    float* out = (float*)d_out;

    unsigned short* ws = (unsigned short*)d_ws;
    const size_t XB_OFF = 0;                               // [32768][512] bf16
    const size_t WT_OFF = XB_OFF + (size_t)NROWS * F_;     // 2x[512][512] bf16
    const size_t QB_OFF = WT_OFF + 2ull * F_ * U_;         // [32768][512] fp8
    const size_t KB_OFF = QB_OFF + (size_t)NROWS * 256;    // (in ushort units)
    const size_t PT_OFF = KB_OFF + (size_t)NROWS * 256;    // [32768][2048] fp8
    const size_t END_USH = PT_OFF + (size_t)B_ * S_ * 1024;
    float* lpart    = (float*)(ws + END_USH);              // [16][2][2048] fp32
    float* wred     = lpart + (size_t)B_ * 2 * 2048;       // [16][8][2048] fp32
    float* xw_parts = wred + (size_t)B_ * 8 * 2048;        // [16][16][512] fp32
    const size_t need = END_USH * 2
                      + ((size_t)B_ * 2 * 2048 + (size_t)B_ * 8 * 2048
                         + (size_t)B_ * 16 * F_) * 4;
    if (ws_size < need) return;

    unsigned short* xb = ws + XB_OFF;
    unsigned short* Wt = ws + WT_OFF;
    unsigned char*  Qb8 = (unsigned char*)(ws + QB_OFF);
    unsigned char*  Kb8 = (unsigned char*)(ws + KB_OFF);
    unsigned char*  pt  = (unsigned char*)(ws + PT_OFF);

    conv_xw<<<2560, 256, 0, stream>>>(x, Wq, Wk, xb, Wt);
    qk_gemm<<<2048, 256, 0, stream>>>(xb, Wt, Qb8, Kb8);
    attn_w<<<512, 256, 0, stream>>>(Qb8, Kb8, pt, lpart);
    w_red<<<2048, 256, 0, stream>>>(pt, lpart, wred);
    xw_part<<<256, 256, 0, stream>>>(x, wred, xw_parts);
    final_out<<<B_, 512, 0, stream>>>(xw_parts, Wv, out);
}